// Round 2
// baseline (288.663 us; speedup 1.0000x reference)
//
#include <hip/hip_runtime.h>
#include <hip/hip_bf16.h>

typedef __bf16 bf16x8 __attribute__((ext_vector_type(8)));
typedef float f32x4 __attribute__((ext_vector_type(4)));
typedef unsigned short ushort8 __attribute__((ext_vector_type(8)));
typedef unsigned short ushort4v __attribute__((ext_vector_type(4)));
typedef float float4v __attribute__((ext_vector_type(4)));

#define N_USERS 8192
#define N_ITEMS 4096
#define BATCH   2048
#define TOPK    10

__device__ __forceinline__ float b2f(unsigned short u) {
    union { unsigned int i; float f; } x;
    x.i = ((unsigned int)u) << 16;
    return x.f;
}

// ---------------------------------------------------------------------------
// Kernel 0: convert fp32 user matrix (exact 0.0/1.0) to bf16 (bit-truncate,
// exact for 0/1) and compute invn[row] = 1/sqrt(count of ones). One block/row.
// ---------------------------------------------------------------------------
__global__ __launch_bounds__(256)
void convert_rows(const float* __restrict__ A, unsigned short* __restrict__ Abf,
                  float* __restrict__ invn) {
    __shared__ float wsum[4];
    const int row  = blockIdx.x;
    const int tid  = threadIdx.x;
    const int wave = tid >> 6;
    const int lane = tid & 63;
    const float* src = A + (size_t)row * N_ITEMS;
    unsigned short* dst = Abf + (size_t)row * N_ITEMS;
    float s = 0.f;
#pragma unroll
    for (int i = 0; i < 4; ++i) {
        const int col = tid * 4 + i * 1024;
        float4v v = *(const float4v*)(src + col);
        ushort4v o;
#pragma unroll
        for (int j = 0; j < 4; ++j) {
            union { float f; unsigned int u; } x; x.f = v[j];
            o[j] = (unsigned short)(x.u >> 16);   // exact for 0.0 / 1.0
            s += v[j];
        }
        *(ushort4v*)(dst + col) = o;
    }
#pragma unroll
    for (int o = 32; o > 0; o >>= 1) s += __shfl_down(s, o);
    if (lane == 0) wsum[wave] = s;
    __syncthreads();
    if (tid == 0) {
        float t = wsum[0] + wsum[1] + wsum[2] + wsum[3];
        invn[row] = (t > 0.f) ? (1.0f / sqrtf(t)) : 0.f;
    }
}

// ---------------------------------------------------------------------------
// Kernel 1: sim[b][n] = dot(Abf[bidx[b]], Abf[n]) * invn[bidx[b]] * invn[n]
// 128x128 tile, BK=32, 4 waves (2x2), mfma_f32_16x16x32_bf16,
// global_load_lds width-16 staging (m97 structure). NT GEMM.
// Epilogue fuses normalization + self-exclusion mask. Dots are exact ints.
// ---------------------------------------------------------------------------
__global__ __launch_bounds__(256)
void sim_gemm(const unsigned short* __restrict__ A,
              const int* __restrict__ bidx,
              const float* __restrict__ invn,
              float* __restrict__ sim) {
    __shared__ unsigned short As[128 * 32];
    __shared__ unsigned short Bs[128 * 32];

    const int tid  = threadIdx.x;
    const int wave = tid >> 6;
    const int lane = tid & 63;
    const int m0   = blockIdx.y * 128;   // batch-row tile
    const int n0   = blockIdx.x * 128;   // user-col tile

    const int colofs = (tid & 3) * 8;          // bf16 elems within row
    const int rA0 = tid >> 2;                  // rows 0..63
    const int rA1 = (tid >> 2) + 64;           // rows 64..127
    const int u0 = bidx[m0 + rA0];
    const int u1 = bidx[m0 + rA1];
    const unsigned short* srcA0 = A + (size_t)u0 * N_ITEMS + colofs;
    const unsigned short* srcA1 = A + (size_t)u1 * N_ITEMS + colofs;
    const unsigned short* srcB0 = A + (size_t)(n0 + rA0) * N_ITEMS + colofs;
    const unsigned short* srcB1 = A + (size_t)(n0 + rA1) * N_ITEMS + colofs;

    char* dA0 = (char*)As + wave * 1024;
    char* dA1 = (char*)As + 4096 + wave * 1024;
    char* dB0 = (char*)Bs + wave * 1024;
    char* dB1 = (char*)Bs + 4096 + wave * 1024;

    const int wr = wave >> 1, wc = wave & 1;
    const int frow = lane & 15;
    const int fks  = (lane >> 4) * 8;

    f32x4 acc[4][4] = {};

    for (int k0 = 0; k0 < N_ITEMS; k0 += 32) {
        __builtin_amdgcn_global_load_lds(
            (const __attribute__((address_space(1))) unsigned int*)(srcA0 + k0),
            (__attribute__((address_space(3))) unsigned int*)dA0, 16, 0, 0);
        __builtin_amdgcn_global_load_lds(
            (const __attribute__((address_space(1))) unsigned int*)(srcA1 + k0),
            (__attribute__((address_space(3))) unsigned int*)dA1, 16, 0, 0);
        __builtin_amdgcn_global_load_lds(
            (const __attribute__((address_space(1))) unsigned int*)(srcB0 + k0),
            (__attribute__((address_space(3))) unsigned int*)dB0, 16, 0, 0);
        __builtin_amdgcn_global_load_lds(
            (const __attribute__((address_space(1))) unsigned int*)(srcB1 + k0),
            (__attribute__((address_space(3))) unsigned int*)dB1, 16, 0, 0);
        __syncthreads();

        bf16x8 af[4], bfr[4];
#pragma unroll
        for (int m = 0; m < 4; ++m)
            af[m] = *(const bf16x8*)(As + (wr * 64 + m * 16 + frow) * 32 + fks);
#pragma unroll
        for (int n = 0; n < 4; ++n)
            bfr[n] = *(const bf16x8*)(Bs + (wc * 64 + n * 16 + frow) * 32 + fks);
#pragma unroll
        for (int m = 0; m < 4; ++m)
#pragma unroll
            for (int n = 0; n < 4; ++n)
                acc[m][n] = __builtin_amdgcn_mfma_f32_16x16x32_bf16(
                    af[m], bfr[n], acc[m][n], 0, 0, 0);
        __syncthreads();
    }

    // epilogue: C/D layout col = lane&15, row = (lane>>4)*4 + j  [m89/m91]
    const int ccol = lane & 15;
#pragma unroll
    for (int m = 0; m < 4; ++m) {
#pragma unroll
        for (int j = 0; j < 4; ++j) {
            const int b  = m0 + wr * 64 + m * 16 + (lane >> 4) * 4 + j;
            const int ub = bidx[b];
            const float inb = invn[ub];
            const size_t rowoff = (size_t)b * N_USERS;
#pragma unroll
            for (int n = 0; n < 4; ++n) {
                const int nn = n0 + wc * 64 + n * 16 + ccol;
                float v = acc[m][n][j] * inb * invn[nn];
                if (nn == ub) v = -1e9f;
                sim[rowoff + nn] = v;
            }
        }
    }
}

// ---------------------------------------------------------------------------
// Kernel 2: per batch row: top-10 (iterative argmax, tie -> lowest index),
// softmax(v/0.5), out = 0.7*pred + 0.3 * sum_k w_k * A[idx_k]
// ---------------------------------------------------------------------------
__global__ __launch_bounds__(256)
void topk_blend(const float* __restrict__ sim,
                const unsigned short* __restrict__ Abf,
                const float* __restrict__ pred,
                float* __restrict__ out) {
    __shared__ float srow[N_USERS];
    __shared__ float wv[4];
    __shared__ int   wi[4];
    __shared__ float topv[TOPK];
    __shared__ int   topi[TOPK];

    const int b    = blockIdx.x;
    const int tid  = threadIdx.x;
    const int wave = tid >> 6;
    const int lane = tid & 63;

    const float* sr = sim + (size_t)b * N_USERS;
    for (int i = tid; i < N_USERS / 4; i += 256)
        ((float4v*)srow)[i] = ((const float4v*)sr)[i];
    __syncthreads();

    for (int it = 0; it < TOPK; ++it) {
        float bv = -1e30f;
        int   bi = 0x7fffffff;
        for (int i = tid; i < N_USERS; i += 256) {
            float v = srow[i];
            if (v > bv) { bv = v; bi = i; }
        }
#pragma unroll
        for (int o = 32; o > 0; o >>= 1) {
            float ov = __shfl_down(bv, o);
            int   oi = __shfl_down(bi, o);
            if (ov > bv || (ov == bv && oi < bi)) { bv = ov; bi = oi; }
        }
        if (lane == 0) { wv[wave] = bv; wi[wave] = bi; }
        __syncthreads();
        if (tid == 0) {
            float fv = wv[0]; int fi = wi[0];
            for (int w = 1; w < 4; ++w)
                if (wv[w] > fv || (wv[w] == fv && wi[w] < fi)) { fv = wv[w]; fi = wi[w]; }
            topv[it] = fv; topi[it] = fi;
            srow[fi] = -1e30f;
        }
        __syncthreads();
    }

    // redundant per-thread softmax over 10 values (registers)
    float w[TOPK];
    int   nid[TOPK];
    float mx = -1e30f;
#pragma unroll
    for (int k = 0; k < TOPK; ++k) mx = fmaxf(mx, topv[k]);
    float sumw = 0.f;
#pragma unroll
    for (int k = 0; k < TOPK; ++k) {
        nid[k] = topi[k];
        w[k] = __expf((topv[k] - mx) * 2.0f);   // 1/TEMP = 2
        sumw += w[k];
    }
    const float scl = 0.3f / sumw;              // fold (1-gamma)
#pragma unroll
    for (int k = 0; k < TOPK; ++k) w[k] *= scl;

    const float* pr = pred + (size_t)b * N_ITEMS;
    float*       po = out  + (size_t)b * N_ITEMS;
#pragma unroll
    for (int h = 0; h < 2; ++h) {
        const int col = h * 2048 + tid * 8;
        float4v p0 = *(const float4v*)(pr + col);
        float4v p1 = *(const float4v*)(pr + col + 4);
        float agg[8];
#pragma unroll
        for (int j = 0; j < 8; ++j) agg[j] = 0.f;
#pragma unroll
        for (int k = 0; k < TOPK; ++k) {
            ushort8 nv = *(const ushort8*)(Abf + (size_t)nid[k] * N_ITEMS + col);
#pragma unroll
            for (int j = 0; j < 8; ++j) agg[j] += w[k] * b2f(nv[j]);
        }
        float4v o0, o1;
#pragma unroll
        for (int j = 0; j < 4; ++j) {
            o0[j] = 0.7f * p0[j] + agg[j];
            o1[j] = 0.7f * p1[j] + agg[j + 4];
        }
        *(float4v*)(po + col)     = o0;
        *(float4v*)(po + col + 4) = o1;
    }
}

extern "C" void kernel_launch(void* const* d_in, const int* in_sizes, int n_in,
                              void* d_out, int out_size, void* d_ws, size_t ws_size,
                              hipStream_t stream) {
    const float* pred = (const float*)d_in[0];
    const float* A    = (const float*)d_in[1];
    const int*   bidx = (const int*)d_in[2];
    float*       out  = (float*)d_out;

    // ws layout: Abf [8192][4096] bf16 = 64 MiB | invn 32 KiB (pad to 64 KiB) | sim [2048][8192] f32 = 64 MiB
    unsigned short* Abf  = (unsigned short*)d_ws;
    float*          invn = (float*)((char*)d_ws + (size_t)N_USERS * N_ITEMS * 2);
    float*          sim  = (float*)((char*)d_ws + (size_t)N_USERS * N_ITEMS * 2 + 65536);

    convert_rows<<<N_USERS, 256, 0, stream>>>(A, Abf, invn);
    sim_gemm<<<dim3(N_USERS / 128, BATCH / 128), 256, 0, stream>>>(Abf, bidx, invn, sim);
    topk_blend<<<BATCH, 256, 0, stream>>>(sim, Abf, pred, out);
}

// Round 3
// 221.628 us; speedup vs baseline: 1.3025x; 1.3025x over previous
//
#include <hip/hip_runtime.h>
#include <hip/hip_bf16.h>

typedef __bf16 bf16x8 __attribute__((ext_vector_type(8)));
typedef float f32x4 __attribute__((ext_vector_type(4)));
typedef unsigned short ushort8 __attribute__((ext_vector_type(8)));
typedef unsigned short ushort4v __attribute__((ext_vector_type(4)));
typedef float float4v __attribute__((ext_vector_type(4)));

#define N_USERS 8192
#define N_ITEMS 4096
#define BATCH   2048
#define TOPK    10
#define NT      64          // K tiles of 64: 4096/64

__device__ __forceinline__ float b2f(unsigned short u) {
    union { unsigned int i; float f; } x;
    x.i = ((unsigned int)u) << 16;
    return x.f;
}

__device__ __forceinline__ void gload16(const unsigned short* src, char* dst) {
    __builtin_amdgcn_global_load_lds(
        (const __attribute__((address_space(1))) unsigned int*)src,
        (__attribute__((address_space(3))) unsigned int*)dst, 16, 0, 0);
}

// ---------------------------------------------------------------------------
// Kernel 0: fp32 (exact 0/1) -> bf16 truncate + invn[row] = rsqrt(count).
// ---------------------------------------------------------------------------
__global__ __launch_bounds__(256)
void convert_rows(const float* __restrict__ A, unsigned short* __restrict__ Abf,
                  float* __restrict__ invn) {
    __shared__ float wsum[4];
    const int row  = blockIdx.x;
    const int tid  = threadIdx.x;
    const int wave = tid >> 6;
    const int lane = tid & 63;
    const float* src = A + (size_t)row * N_ITEMS;
    unsigned short* dst = Abf + (size_t)row * N_ITEMS;
    float s = 0.f;
#pragma unroll
    for (int i = 0; i < 4; ++i) {
        const int col = tid * 4 + i * 1024;
        float4v v = *(const float4v*)(src + col);
        ushort4v o;
#pragma unroll
        for (int j = 0; j < 4; ++j) {
            union { float f; unsigned int u; } x; x.f = v[j];
            o[j] = (unsigned short)(x.u >> 16);
            s += v[j];
        }
        *(ushort4v*)(dst + col) = o;
    }
#pragma unroll
    for (int o = 32; o > 0; o >>= 1) s += __shfl_down(s, o);
    if (lane == 0) wsum[wave] = s;
    __syncthreads();
    if (tid == 0) {
        float t = wsum[0] + wsum[1] + wsum[2] + wsum[3];
        invn[row] = (t > 0.f) ? (1.0f / sqrtf(t)) : 0.f;
    }
}

// ---------------------------------------------------------------------------
// Kernel 1: 256x256 8-phase GEMM (T2+T3+T4+T5).
// sim[b][n] = dot(Abf[bidx[b]], Abf[n]) * invn[bidx[b]] * invn[n]; self = -1e9.
// BK=64; 8 waves (2M x 4N); LDS 128 KiB = 2 dbuf x {A,B} x 2 halves [128][64].
// Wave (wr,wc) reads A-half wr, B-half wc>>1 only. XOR swizzle ((row&7)<<4)
// on col byte; stage pre-swizzles the GLOBAL source col (linear LDS dest).
// ---------------------------------------------------------------------------
#define BAR_MID() do { __builtin_amdgcn_s_barrier(); \
    asm volatile("s_waitcnt lgkmcnt(0)" ::: "memory"); \
    __builtin_amdgcn_sched_barrier(0); \
    __builtin_amdgcn_s_setprio(1); } while (0)

#define BAR_END() do { __builtin_amdgcn_s_setprio(0); \
    __builtin_amdgcn_sched_barrier(0); \
    __builtin_amdgcn_s_barrier(); } while (0)

#define BAR_END_VM2() do { __builtin_amdgcn_s_setprio(0); \
    __builtin_amdgcn_sched_barrier(0); \
    asm volatile("s_waitcnt vmcnt(2)" ::: "memory"); \
    __builtin_amdgcn_sched_barrier(0); \
    __builtin_amdgcn_s_barrier(); } while (0)

#define BAR_END_VM0() do { __builtin_amdgcn_s_setprio(0); \
    __builtin_amdgcn_sched_barrier(0); \
    asm volatile("s_waitcnt vmcnt(0)" ::: "memory"); \
    __builtin_amdgcn_sched_barrier(0); \
    __builtin_amdgcn_s_barrier(); } while (0)

#define RD_A4(dst, bo, mofs) \
  _Pragma("unroll") for (int m_ = 0; m_ < 4; ++m_) { \
    dst[m_*2+0] = *(const bf16x8*)(lds + (bo) + arowb + (m_+(mofs))*2048 + cb0); \
    dst[m_*2+1] = *(const bf16x8*)(lds + (bo) + arowb + (m_+(mofs))*2048 + cb1); }

#define RD_B2(dst, bo, nofs) \
  _Pragma("unroll") for (int n_ = 0; n_ < 2; ++n_) { \
    dst[n_*2+0] = *(const bf16x8*)(lds + (bo) + browb + (n_+(nofs))*2048 + cb0); \
    dst[n_*2+1] = *(const bf16x8*)(lds + (bo) + browb + (n_+(nofs))*2048 + cb1); }

#define MMA4x2(afr, bfr, mofs, nofs) \
  _Pragma("unroll") for (int m_ = 0; m_ < 4; ++m_) \
  _Pragma("unroll") for (int n_ = 0; n_ < 2; ++n_) { \
    acc[m_+(mofs)][n_+(nofs)] = __builtin_amdgcn_mfma_f32_16x16x32_bf16( \
        afr[m_*2+0], bfr[n_*2+0], acc[m_+(mofs)][n_+(nofs)], 0, 0, 0); \
    acc[m_+(mofs)][n_+(nofs)] = __builtin_amdgcn_mfma_f32_16x16x32_bf16( \
        afr[m_*2+1], bfr[n_*2+1], acc[m_+(mofs)][n_+(nofs)], 0, 0, 0); }

// Window = 4 phases computing one K-tile from buffer `bo`, with per-phase
// stage statements S0..S3 and the window-closing wait/barrier ENDW.
#define WINDOW(bo, S0, S1, S2, S3, ENDW) do { \
    RD_A4(af,  bo, 0); RD_B2(bf01, bo, 0); S0; \
    BAR_MID(); MMA4x2(af,  bf01, 0, 0); BAR_END(); \
    RD_B2(bf23, bo, 2); S1; \
    BAR_MID(); MMA4x2(af,  bf23, 0, 2); BAR_END(); \
    RD_A4(af2, bo, 4); S2; \
    BAR_MID(); MMA4x2(af2, bf01, 4, 0); BAR_END(); \
    S3; \
    BAR_MID(); MMA4x2(af2, bf23, 4, 2); ENDW; \
} while (0)

__global__ __launch_bounds__(512, 2)
void sim_gemm8(const unsigned short* __restrict__ A,
               const int* __restrict__ bidx,
               const float* __restrict__ invn,
               float* __restrict__ sim) {
    __shared__ char lds[131072];

    const int tid  = threadIdx.x;
    const int w    = tid >> 6;
    const int lane = tid & 63;
    const int m0   = blockIdx.y * 256;
    const int n0   = blockIdx.x * 256;
    const int wr = w >> 2, wc = w & 3;

    // fragment-read addressing (swizzled)
    const int fr = lane & 15, ks = lane >> 4;
    const int swz = (fr & 7) << 4;
    const int cb0 = (ks * 16) ^ swz;
    const int cb1 = (ks * 16 + 64) ^ swz;
    const int arowb = wr * 16384 + fr * 128;                       // A region
    const int browb = 32768 + (wc >> 1) * 16384 + ((wc & 1) * 64 + fr) * 128;

    // staging source pointers (global col pre-swizzled; LDS dest stays linear)
    const int sr = lane >> 3;                        // row-subgroup 0..7
    const int swzcol = ((lane & 7) ^ sr) * 8;        // elems
    const unsigned short* pA[4];
    const unsigned short* pB[4];
#pragma unroll
    for (int g = 0; g < 4; ++g) {
        const int row = g * 64 + w * 8 + sr;
        pA[g] = A + (size_t)bidx[m0 + row] * N_ITEMS + swzcol;
        pB[g] = A + (size_t)(n0 + row) * N_ITEMS + swzcol;
    }

    f32x4 acc[8][4] = {};
    bf16x8 af[8], af2[8], bf01[4], bf23[4];

#define STA(U, h) do { \
    char* d_ = lds + (((U) & 1) * 65536) + (h) * 16384 + w * 1024; \
    const int k0_ = (U) * 64; \
    gload16(pA[(h)*2+0] + k0_, d_); \
    gload16(pA[(h)*2+1] + k0_, d_ + 8192); } while (0)

#define STB(U, h) do { \
    char* d_ = lds + (((U) & 1) * 65536) + 32768 + (h) * 16384 + w * 1024; \
    const int k0_ = (U) * 64; \
    gload16(pB[(h)*2+0] + k0_, d_); \
    gload16(pB[(h)*2+1] + k0_, d_ + 8192); } while (0)

    // prologue: tile0 fully + tile1.A0; leave tile1.A0 in flight
    STA(0, 0); STA(0, 1); STB(0, 0); STB(0, 1); STA(1, 0);
    asm volatile("s_waitcnt vmcnt(2)" ::: "memory");
    __builtin_amdgcn_s_barrier();

    for (int i = 0; i < 31; ++i) {
        const int t1 = 2 * i + 1, t2 = 2 * i + 2, t3 = 2 * i + 3;
        WINDOW(0, STA(t1, 1), STB(t1, 0), STB(t1, 1), STA(t2, 0), BAR_END_VM2());
        WINDOW(65536, STA(t2, 1), STB(t2, 0), STB(t2, 1), STA(t3, 0), BAR_END_VM2());
    }
    // epilogue: tiles 62 (buf0) and 63 (buf1)
    WINDOW(0, STA(63, 1), STB(63, 0), STB(63, 1), (void)0, BAR_END_VM0());
    WINDOW(65536, (void)0, (void)0, (void)0, (void)0, BAR_END());

    // C epilogue: fuse normalization + self-mask; C/D: col=lane&15, row=ks*4+j
    const int crow_base = m0 + wr * 128 + ks * 4;
    const int ccol_base = n0 + wc * 64 + fr;
#pragma unroll
    for (int mf = 0; mf < 8; ++mf) {
#pragma unroll
        for (int j = 0; j < 4; ++j) {
            const int b  = crow_base + mf * 16 + j;
            const int ub = bidx[b];
            const float inb = invn[ub];
            float* rp = sim + (size_t)b * N_USERS;
#pragma unroll
            for (int nf = 0; nf < 4; ++nf) {
                const int nn = ccol_base + nf * 16;
                float v = acc[mf][nf][j] * inb * invn[nn];
                if (nn == ub) v = -1e9f;
                rp[nn] = v;
            }
        }
    }
#undef STA
#undef STB
}

// ---------------------------------------------------------------------------
// Kernel 2: per batch row: top-10 (iterative argmax, tie -> lowest index),
// softmax(v/0.5), out = 0.7*pred + 0.3 * sum_k w_k * A[idx_k]
// ---------------------------------------------------------------------------
__global__ __launch_bounds__(256)
void topk_blend(const float* __restrict__ sim,
                const unsigned short* __restrict__ Abf,
                const float* __restrict__ pred,
                float* __restrict__ out) {
    __shared__ float srow[N_USERS];
    __shared__ float wv[4];
    __shared__ int   wi[4];
    __shared__ float topv[TOPK];
    __shared__ int   topi[TOPK];

    const int b    = blockIdx.x;
    const int tid  = threadIdx.x;
    const int wave = tid >> 6;
    const int lane = tid & 63;

    const float* sr = sim + (size_t)b * N_USERS;
    for (int i = tid; i < N_USERS / 4; i += 256)
        ((float4v*)srow)[i] = ((const float4v*)sr)[i];
    __syncthreads();

    for (int it = 0; it < TOPK; ++it) {
        float bv = -1e30f;
        int   bi = 0x7fffffff;
        for (int i = tid; i < N_USERS; i += 256) {
            float v = srow[i];
            if (v > bv) { bv = v; bi = i; }
        }
#pragma unroll
        for (int o = 32; o > 0; o >>= 1) {
            float ov = __shfl_down(bv, o);
            int   oi = __shfl_down(bi, o);
            if (ov > bv || (ov == bv && oi < bi)) { bv = ov; bi = oi; }
        }
        if (lane == 0) { wv[wave] = bv; wi[wave] = bi; }
        __syncthreads();
        if (tid == 0) {
            float fv = wv[0]; int fi = wi[0];
            for (int ww = 1; ww < 4; ++ww)
                if (wv[ww] > fv || (wv[ww] == fv && wi[ww] < fi)) { fv = wv[ww]; fi = wi[ww]; }
            topv[it] = fv; topi[it] = fi;
            srow[fi] = -1e30f;
        }
        __syncthreads();
    }

    float w[TOPK];
    int   nid[TOPK];
    float mx = -1e30f;
#pragma unroll
    for (int k = 0; k < TOPK; ++k) mx = fmaxf(mx, topv[k]);
    float sumw = 0.f;
#pragma unroll
    for (int k = 0; k < TOPK; ++k) {
        nid[k] = topi[k];
        w[k] = __expf((topv[k] - mx) * 2.0f);   // 1/TEMP = 2
        sumw += w[k];
    }
    const float scl = 0.3f / sumw;              // fold (1-gamma)
#pragma unroll
    for (int k = 0; k < TOPK; ++k) w[k] *= scl;

    const float* pr = pred + (size_t)b * N_ITEMS;
    float*       po = out  + (size_t)b * N_ITEMS;
#pragma unroll
    for (int h = 0; h < 2; ++h) {
        const int col = h * 2048 + tid * 8;
        float4v p0 = *(const float4v*)(pr + col);
        float4v p1 = *(const float4v*)(pr + col + 4);
        float agg[8];
#pragma unroll
        for (int j = 0; j < 8; ++j) agg[j] = 0.f;
#pragma unroll
        for (int k = 0; k < TOPK; ++k) {
            ushort8 nv = *(const ushort8*)(Abf + (size_t)nid[k] * N_ITEMS + col);
#pragma unroll
            for (int j = 0; j < 8; ++j) agg[j] += w[k] * b2f(nv[j]);
        }
        float4v o0, o1;
#pragma unroll
        for (int j = 0; j < 4; ++j) {
            o0[j] = 0.7f * p0[j] + agg[j];
            o1[j] = 0.7f * p1[j] + agg[j + 4];
        }
        *(float4v*)(po + col)     = o0;
        *(float4v*)(po + col + 4) = o1;
    }
}

extern "C" void kernel_launch(void* const* d_in, const int* in_sizes, int n_in,
                              void* d_out, int out_size, void* d_ws, size_t ws_size,
                              hipStream_t stream) {
    const float* pred = (const float*)d_in[0];
    const float* A    = (const float*)d_in[1];
    const int*   bidx = (const int*)d_in[2];
    float*       out  = (float*)d_out;

    unsigned short* Abf  = (unsigned short*)d_ws;                               // 64 MiB
    float*          invn = (float*)((char*)d_ws + (size_t)N_USERS * N_ITEMS * 2);
    float*          sim  = (float*)((char*)d_ws + (size_t)N_USERS * N_ITEMS * 2 + 65536);

    convert_rows<<<N_USERS, 256, 0, stream>>>(A, Abf, invn);
    sim_gemm8<<<dim3(N_USERS / 256, BATCH / 256), 512, 0, stream>>>(Abf, bidx, invn, sim);
    topk_blend<<<BATCH, 256, 0, stream>>>(sim, Abf, pred, out);
}

// Round 4
// 196.921 us; speedup vs baseline: 1.4659x; 1.1255x over previous
//
#include <hip/hip_runtime.h>
#include <hip/hip_bf16.h>

typedef __bf16 bf16x8 __attribute__((ext_vector_type(8)));
typedef float f32x4 __attribute__((ext_vector_type(4)));
typedef unsigned short ushort8 __attribute__((ext_vector_type(8)));
typedef unsigned short ushort4v __attribute__((ext_vector_type(4)));
typedef float float4v __attribute__((ext_vector_type(4)));

#define N_USERS 8192
#define N_ITEMS 4096
#define BATCH   2048
#define TOPK    10

__device__ __forceinline__ float b2f(unsigned short u) {
    union { unsigned int i; float f; } x;
    x.i = ((unsigned int)u) << 16;
    return x.f;
}

__device__ __forceinline__ void gload16(const unsigned short* src, char* dst) {
    __builtin_amdgcn_global_load_lds(
        (const __attribute__((address_space(1))) unsigned int*)src,
        (__attribute__((address_space(3))) unsigned int*)dst, 16, 0, 0);
}

// ---------------------------------------------------------------------------
// Kernel 0: fp32 (exact 0/1) -> bf16 truncate + invn[row] = rsqrt(count).
// ---------------------------------------------------------------------------
__global__ __launch_bounds__(256)
void convert_rows(const float* __restrict__ A, unsigned short* __restrict__ Abf,
                  float* __restrict__ invn) {
    __shared__ float wsum[4];
    const int row  = blockIdx.x;
    const int tid  = threadIdx.x;
    const int wave = tid >> 6;
    const int lane = tid & 63;
    const float* src = A + (size_t)row * N_ITEMS;
    unsigned short* dst = Abf + (size_t)row * N_ITEMS;
    float s = 0.f;
#pragma unroll
    for (int i = 0; i < 4; ++i) {
        const int col = tid * 4 + i * 1024;
        float4v v = *(const float4v*)(src + col);
        ushort4v o;
#pragma unroll
        for (int j = 0; j < 4; ++j) {
            union { float f; unsigned int u; } x; x.f = v[j];
            o[j] = (unsigned short)(x.u >> 16);
            s += v[j];
        }
        *(ushort4v*)(dst + col) = o;
    }
#pragma unroll
    for (int o = 32; o > 0; o >>= 1) s += __shfl_down(s, o);
    if (lane == 0) wsum[wave] = s;
    __syncthreads();
    if (tid == 0) {
        float t = wsum[0] + wsum[1] + wsum[2] + wsum[3];
        invn[row] = (t > 0.f) ? (1.0f / sqrtf(t)) : 0.f;
    }
}

// ---------------------------------------------------------------------------
// Kernel 1: 256x256 8-phase GEMM (T2+T3+T4+T5), deepened pipeline:
// window for tile t stages B(t+1) in S0/S1 and A(t+2) in S2/S3; window end
// drains to vmcnt(4) (A(t+2) stays in flight). Latency budget 2.5 phases.
// ---------------------------------------------------------------------------
#define BAR_MID() do { __builtin_amdgcn_s_barrier(); \
    asm volatile("s_waitcnt lgkmcnt(0)" ::: "memory"); \
    __builtin_amdgcn_sched_barrier(0); \
    __builtin_amdgcn_s_setprio(1); } while (0)

#define BAR_END() do { __builtin_amdgcn_s_setprio(0); \
    __builtin_amdgcn_sched_barrier(0); \
    __builtin_amdgcn_s_barrier(); } while (0)

#define BAR_END_VM4() do { __builtin_amdgcn_s_setprio(0); \
    __builtin_amdgcn_sched_barrier(0); \
    asm volatile("s_waitcnt vmcnt(4)" ::: "memory"); \
    __builtin_amdgcn_sched_barrier(0); \
    __builtin_amdgcn_s_barrier(); } while (0)

#define BAR_END_VM0() do { __builtin_amdgcn_s_setprio(0); \
    __builtin_amdgcn_sched_barrier(0); \
    asm volatile("s_waitcnt vmcnt(0)" ::: "memory"); \
    __builtin_amdgcn_sched_barrier(0); \
    __builtin_amdgcn_s_barrier(); } while (0)

#define RD_A4(dst, bo, mofs) \
  _Pragma("unroll") for (int m_ = 0; m_ < 4; ++m_) { \
    dst[m_*2+0] = *(const bf16x8*)(lds + (bo) + arowb + (m_+(mofs))*2048 + cb0); \
    dst[m_*2+1] = *(const bf16x8*)(lds + (bo) + arowb + (m_+(mofs))*2048 + cb1); }

#define RD_B2(dst, bo, nofs) \
  _Pragma("unroll") for (int n_ = 0; n_ < 2; ++n_) { \
    dst[n_*2+0] = *(const bf16x8*)(lds + (bo) + browb + (n_+(nofs))*2048 + cb0); \
    dst[n_*2+1] = *(const bf16x8*)(lds + (bo) + browb + (n_+(nofs))*2048 + cb1); }

#define MMA4x2(afr, bfr, mofs, nofs) \
  _Pragma("unroll") for (int m_ = 0; m_ < 4; ++m_) \
  _Pragma("unroll") for (int n_ = 0; n_ < 2; ++n_) { \
    acc[m_+(mofs)][n_+(nofs)] = __builtin_amdgcn_mfma_f32_16x16x32_bf16( \
        afr[m_*2+0], bfr[n_*2+0], acc[m_+(mofs)][n_+(nofs)], 0, 0, 0); \
    acc[m_+(mofs)][n_+(nofs)] = __builtin_amdgcn_mfma_f32_16x16x32_bf16( \
        afr[m_*2+1], bfr[n_*2+1], acc[m_+(mofs)][n_+(nofs)], 0, 0, 0); }

#define WINDOW(bo, S0, S1, S2, S3, ENDW) do { \
    RD_A4(af,  bo, 0); RD_B2(bf01, bo, 0); S0; \
    BAR_MID(); MMA4x2(af,  bf01, 0, 0); BAR_END(); \
    RD_B2(bf23, bo, 2); S1; \
    BAR_MID(); MMA4x2(af,  bf23, 0, 2); BAR_END(); \
    RD_A4(af2, bo, 4); S2; \
    BAR_MID(); MMA4x2(af2, bf01, 4, 0); BAR_END(); \
    S3; \
    BAR_MID(); MMA4x2(af2, bf23, 4, 2); ENDW; \
} while (0)

__global__ __launch_bounds__(512, 2)
void sim_gemm8(const unsigned short* __restrict__ A,
               const int* __restrict__ bidx,
               const float* __restrict__ invn,
               float* __restrict__ sim) {
    __shared__ char lds[131072];

    const int tid  = threadIdx.x;
    const int w    = tid >> 6;
    const int lane = tid & 63;
    const int m0   = blockIdx.y * 256;
    const int n0   = blockIdx.x * 256;
    const int wr = w >> 2, wc = w & 3;

    const int fr = lane & 15, ks = lane >> 4;
    const int swz = (fr & 7) << 4;
    const int cb0 = (ks * 16) ^ swz;
    const int cb1 = (ks * 16 + 64) ^ swz;
    const int arowb = wr * 16384 + fr * 128;
    const int browb = 32768 + (wc >> 1) * 16384 + ((wc & 1) * 64 + fr) * 128;

    const int sr = lane >> 3;
    const int swzcol = ((lane & 7) ^ sr) * 8;
    const unsigned short* pA[4];
    const unsigned short* pB[4];
#pragma unroll
    for (int g = 0; g < 4; ++g) {
        const int row = g * 64 + w * 8 + sr;
        pA[g] = A + (size_t)bidx[m0 + row] * N_ITEMS + swzcol;
        pB[g] = A + (size_t)(n0 + row) * N_ITEMS + swzcol;
    }

    f32x4 acc[8][4] = {};
    bf16x8 af[8], af2[8], bf01[4], bf23[4];

#define STA(U, h) do { \
    char* d_ = lds + (((U) & 1) * 65536) + (h) * 16384 + w * 1024; \
    const int k0_ = (U) * 64; \
    gload16(pA[(h)*2+0] + k0_, d_); \
    gload16(pA[(h)*2+1] + k0_, d_ + 8192); } while (0)

#define STB(U, h) do { \
    char* d_ = lds + (((U) & 1) * 65536) + 32768 + (h) * 16384 + w * 1024; \
    const int k0_ = (U) * 64; \
    gload16(pB[(h)*2+0] + k0_, d_); \
    gload16(pB[(h)*2+1] + k0_, d_ + 8192); } while (0)

    // prologue: tile0 fully + tile1.A0+A1; drain tile0, keep tile1.A in flight
    STA(0, 0); STA(0, 1); STB(0, 0); STB(0, 1); STA(1, 0); STA(1, 1);
    asm volatile("s_waitcnt vmcnt(4)" ::: "memory");
    __builtin_amdgcn_s_barrier();

    for (int i = 0; i < 31; ++i) {
        const int t1 = 2 * i + 1, t2 = 2 * i + 2, t3 = 2 * i + 3;
        WINDOW(0,     STB(t1, 0), STB(t1, 1), STA(t2, 0), STA(t2, 1), BAR_END_VM4());
        WINDOW(65536, STB(t2, 0), STB(t2, 1), STA(t3, 0), STA(t3, 1), BAR_END_VM4());
    }
    // t=62 (buf0): stage B(63) only, drain fully; t=63 (buf1): bare
    WINDOW(0,     STB(63, 0), STB(63, 1), (void)0, (void)0, BAR_END_VM0());
    WINDOW(65536, (void)0, (void)0, (void)0, (void)0, BAR_END());

    // C epilogue: fuse normalization + self-mask; C/D: col=lane&15, row=ks*4+j
    const int crow_base = m0 + wr * 128 + ks * 4;
    const int ccol_base = n0 + wc * 64 + fr;
#pragma unroll
    for (int mf = 0; mf < 8; ++mf) {
#pragma unroll
        for (int j = 0; j < 4; ++j) {
            const int b  = crow_base + mf * 16 + j;
            const int ub = bidx[b];
            const float inb = invn[ub];
            float* rp = sim + (size_t)b * N_USERS;
#pragma unroll
            for (int nf = 0; nf < 4; ++nf) {
                const int nn = ccol_base + nf * 16;
                float v = acc[mf][nf][j] * inb * invn[nn];
                if (nn == ub) v = -1e9f;
                rp[nn] = v;
            }
        }
    }
#undef STA
#undef STB
}

// ---------------------------------------------------------------------------
// Kernel 2: per batch row: top-10 via hierarchical argmax (per-thread chunk
// bests + shfl_xor butterfly over 256 bests; only the owner rescans its 32
// elems). Tie -> lowest index (matches lax.top_k stability). Then
// softmax(v/0.5) in registers, out = 0.7*pred + 0.3 * sum_k w_k * A[idx_k].
// ---------------------------------------------------------------------------
__global__ __launch_bounds__(256)
void topk_blend(const float* __restrict__ sim,
                const unsigned short* __restrict__ Abf,
                const float* __restrict__ pred,
                float* __restrict__ out) {
    __shared__ float srow[N_USERS];
    __shared__ float bvs[256];
    __shared__ int   bis[256];

    const int b    = blockIdx.x;
    const int tid  = threadIdx.x;
    const int lane = tid & 63;

    // stage row to LDS; compute per-thread best over owned slots {tid+256k}
    const float* sr = sim + (size_t)b * N_USERS;
    float bv = -1e30f; int bi = 0x7fffffff;
#pragma unroll
    for (int k = 0; k < 8; ++k) {
        const int slot = tid + k * 256;                 // float4 slot
        float4v v = ((const float4v*)sr)[slot];
        *(float4v*)(srow + slot * 4) = v;
#pragma unroll
        for (int j = 0; j < 4; ++j)
            if (v[j] > bv) { bv = v[j]; bi = slot * 4 + j; }   // k,j ascending => lowest idx kept
    }
    bvs[tid] = bv; bis[tid] = bi;
    __syncthreads();

    float topv[TOPK]; int topi[TOPK];
#pragma unroll
    for (int it = 0; it < TOPK; ++it) {
        // every lane reduces 4 entries, then 6-step butterfly (all lanes get winner)
        float fv = bvs[lane]; int fi = bis[lane];
#pragma unroll
        for (int g = 1; g < 4; ++g) {
            float v2 = bvs[lane + g * 64]; int i2 = bis[lane + g * 64];
            if (v2 > fv || (v2 == fv && i2 < fi)) { fv = v2; fi = i2; }
        }
#pragma unroll
        for (int o = 1; o < 64; o <<= 1) {
            float ov = __shfl_xor(fv, o);
            int   oi = __shfl_xor(fi, o);
            if (ov > fv || (ov == fv && oi < fi)) { fv = ov; fi = oi; }
        }
        topv[it] = fv; topi[it] = fi;
        __syncthreads();                    // all reads of bvs/srow complete
        if (tid == ((fi >> 2) & 255)) {     // owner: knock out + rescan 32 elems
            srow[fi] = -1e30f;
            float nb = -1e30f; int ni = 0x7fffffff;
#pragma unroll
            for (int k = 0; k < 8; ++k) {
                const int slot = tid + k * 256;
                float4v v = *(const float4v*)(srow + slot * 4);
#pragma unroll
                for (int j = 0; j < 4; ++j)
                    if (v[j] > nb) { nb = v[j]; ni = slot * 4 + j; }
            }
            bvs[tid] = nb; bis[tid] = ni;
        }
        __syncthreads();
    }

    // softmax over 10 (registers, redundant per thread)
    float w[TOPK];
    float mx = -1e30f;
#pragma unroll
    for (int k = 0; k < TOPK; ++k) mx = fmaxf(mx, topv[k]);
    float sumw = 0.f;
#pragma unroll
    for (int k = 0; k < TOPK; ++k) {
        w[k] = __expf((topv[k] - mx) * 2.0f);   // 1/TEMP = 2
        sumw += w[k];
    }
    const float scl = 0.3f / sumw;              // fold (1-gamma)
#pragma unroll
    for (int k = 0; k < TOPK; ++k) w[k] *= scl;

    const float* pr = pred + (size_t)b * N_ITEMS;
    float*       po = out  + (size_t)b * N_ITEMS;
#pragma unroll
    for (int h = 0; h < 2; ++h) {
        const int col = h * 2048 + tid * 8;
        float4v p0 = *(const float4v*)(pr + col);
        float4v p1 = *(const float4v*)(pr + col + 4);
        float agg[8];
#pragma unroll
        for (int j = 0; j < 8; ++j) agg[j] = 0.f;
#pragma unroll
        for (int k = 0; k < TOPK; ++k) {
            ushort8 nv = *(const ushort8*)(Abf + (size_t)topi[k] * N_ITEMS + col);
#pragma unroll
            for (int j = 0; j < 8; ++j) agg[j] += w[k] * b2f(nv[j]);
        }
        float4v o0, o1;
#pragma unroll
        for (int j = 0; j < 4; ++j) {
            o0[j] = 0.7f * p0[j] + agg[j];
            o1[j] = 0.7f * p1[j] + agg[j + 4];
        }
        *(float4v*)(po + col)     = o0;
        *(float4v*)(po + col + 4) = o1;
    }
}

extern "C" void kernel_launch(void* const* d_in, const int* in_sizes, int n_in,
                              void* d_out, int out_size, void* d_ws, size_t ws_size,
                              hipStream_t stream) {
    const float* pred = (const float*)d_in[0];
    const float* A    = (const float*)d_in[1];
    const int*   bidx = (const int*)d_in[2];
    float*       out  = (float*)d_out;

    unsigned short* Abf  = (unsigned short*)d_ws;                               // 64 MiB
    float*          invn = (float*)((char*)d_ws + (size_t)N_USERS * N_ITEMS * 2);
    float*          sim  = (float*)((char*)d_ws + (size_t)N_USERS * N_ITEMS * 2 + 65536);

    convert_rows<<<N_USERS, 256, 0, stream>>>(A, Abf, invn);
    sim_gemm8<<<dim3(N_USERS / 256, BATCH / 256), 512, 0, stream>>>(Abf, bidx, invn, sim);
    topk_blend<<<BATCH, 256, 0, stream>>>(sim, Abf, pred, out);
}

// Round 5
// 139.408 us; speedup vs baseline: 2.0706x; 1.4126x over previous
//
#include <hip/hip_runtime.h>
#include <hip/hip_bf16.h>

typedef int i32x4 __attribute__((ext_vector_type(4)));
typedef float f32x4 __attribute__((ext_vector_type(4)));
typedef unsigned char uchar8 __attribute__((ext_vector_type(8)));
typedef unsigned char uchar4v __attribute__((ext_vector_type(4)));
typedef float float4v __attribute__((ext_vector_type(4)));

#define N_USERS 8192
#define N_ITEMS 4096
#define BATCH   2048
#define TOPK    10

__device__ __forceinline__ void gload16(const unsigned char* src, char* dst) {
    __builtin_amdgcn_global_load_lds(
        (const __attribute__((address_space(1))) unsigned int*)src,
        (__attribute__((address_space(3))) unsigned int*)dst, 16, 0, 0);
}

// ---------------------------------------------------------------------------
// Kernel 0: fp32 (exact 0/1) -> i8 + invn[row] = rsqrt(count). One block/row.
// ---------------------------------------------------------------------------
__global__ __launch_bounds__(256)
void convert_rows(const float* __restrict__ A, unsigned char* __restrict__ Ai8,
                  float* __restrict__ invn) {
    __shared__ float wsum[4];
    const int row  = blockIdx.x;
    const int tid  = threadIdx.x;
    const int wave = tid >> 6;
    const int lane = tid & 63;
    const float* src = A + (size_t)row * N_ITEMS;
    unsigned char* dst = Ai8 + (size_t)row * N_ITEMS;
    float s = 0.f;
#pragma unroll
    for (int i = 0; i < 4; ++i) {
        const int col = tid * 4 + i * 1024;
        float4v v = *(const float4v*)(src + col);
        uchar4v o;
#pragma unroll
        for (int j = 0; j < 4; ++j) {
            o[j] = (unsigned char)(v[j] != 0.f);
            s += v[j];
        }
        *(uchar4v*)(dst + col) = o;
    }
#pragma unroll
    for (int o = 32; o > 0; o >>= 1) s += __shfl_down(s, o);
    if (lane == 0) wsum[wave] = s;
    __syncthreads();
    if (tid == 0) {
        float t = wsum[0] + wsum[1] + wsum[2] + wsum[3];
        invn[row] = (t > 0.f) ? (1.0f / sqrtf(t)) : 0.f;
    }
}

// ---------------------------------------------------------------------------
// Kernel 1: 256x256 8-phase GEMM, i8 (exact 0/1 data -> exact i32 dots).
// mfma_i32_16x16x64_i8, BK=128. Byte geometry identical to the verified bf16
// BK=64 layout: rows 128 B, halves 16 KiB, LDS 128 KiB, same XOR swizzle.
// 32 K-tiles (was 64); window stages B(t+1) in S0/S1, A(t+2) in S2/S3,
// drains to vmcnt(4); never vmcnt(0) mid-loop.
// ---------------------------------------------------------------------------
#define BAR_MID() do { __builtin_amdgcn_s_barrier(); \
    asm volatile("s_waitcnt lgkmcnt(0)" ::: "memory"); \
    __builtin_amdgcn_sched_barrier(0); \
    __builtin_amdgcn_s_setprio(1); } while (0)

#define BAR_END() do { __builtin_amdgcn_s_setprio(0); \
    __builtin_amdgcn_sched_barrier(0); \
    __builtin_amdgcn_s_barrier(); } while (0)

#define BAR_END_VM4() do { __builtin_amdgcn_s_setprio(0); \
    __builtin_amdgcn_sched_barrier(0); \
    asm volatile("s_waitcnt vmcnt(4)" ::: "memory"); \
    __builtin_amdgcn_sched_barrier(0); \
    __builtin_amdgcn_s_barrier(); } while (0)

#define BAR_END_VM0() do { __builtin_amdgcn_s_setprio(0); \
    __builtin_amdgcn_sched_barrier(0); \
    asm volatile("s_waitcnt vmcnt(0)" ::: "memory"); \
    __builtin_amdgcn_sched_barrier(0); \
    __builtin_amdgcn_s_barrier(); } while (0)

#define RD_A4(dst, bo, mofs) \
  _Pragma("unroll") for (int m_ = 0; m_ < 4; ++m_) { \
    dst[m_*2+0] = *(const i32x4*)(lds + (bo) + arowb + (m_+(mofs))*2048 + cb0); \
    dst[m_*2+1] = *(const i32x4*)(lds + (bo) + arowb + (m_+(mofs))*2048 + cb1); }

#define RD_B2(dst, bo, nofs) \
  _Pragma("unroll") for (int n_ = 0; n_ < 2; ++n_) { \
    dst[n_*2+0] = *(const i32x4*)(lds + (bo) + browb + (n_+(nofs))*2048 + cb0); \
    dst[n_*2+1] = *(const i32x4*)(lds + (bo) + browb + (n_+(nofs))*2048 + cb1); }

#define MMA4x2(afr, bfr, mofs, nofs) \
  _Pragma("unroll") for (int m_ = 0; m_ < 4; ++m_) \
  _Pragma("unroll") for (int n_ = 0; n_ < 2; ++n_) { \
    acc[m_+(mofs)][n_+(nofs)] = __builtin_amdgcn_mfma_i32_16x16x64_i8( \
        afr[m_*2+0], bfr[n_*2+0], acc[m_+(mofs)][n_+(nofs)], 0, 0, 0); \
    acc[m_+(mofs)][n_+(nofs)] = __builtin_amdgcn_mfma_i32_16x16x64_i8( \
        afr[m_*2+1], bfr[n_*2+1], acc[m_+(mofs)][n_+(nofs)], 0, 0, 0); }

#define WINDOW(bo, S0, S1, S2, S3, ENDW) do { \
    RD_A4(af,  bo, 0); RD_B2(bf01, bo, 0); S0; \
    BAR_MID(); MMA4x2(af,  bf01, 0, 0); BAR_END(); \
    RD_B2(bf23, bo, 2); S1; \
    BAR_MID(); MMA4x2(af,  bf23, 0, 2); BAR_END(); \
    RD_A4(af2, bo, 4); S2; \
    BAR_MID(); MMA4x2(af2, bf01, 4, 0); BAR_END(); \
    S3; \
    BAR_MID(); MMA4x2(af2, bf23, 4, 2); ENDW; \
} while (0)

__global__ __launch_bounds__(512, 2)
void sim_gemm8(const unsigned char* __restrict__ A,
               const int* __restrict__ bidx,
               const float* __restrict__ invn,
               float* __restrict__ sim) {
    __shared__ char lds[131072];

    const int tid  = threadIdx.x;
    const int w    = tid >> 6;
    const int lane = tid & 63;
    const int m0   = blockIdx.y * 256;
    const int n0   = blockIdx.x * 256;
    const int wr = w >> 2, wc = w & 3;

    // fragment reads: row = lane&15 within half, k-chunk = (lane>>4)*16 bytes,
    // second MFMA of the pair at +64 bytes (k 64..127). Same bytes as bf16 ver.
    const int fr = lane & 15, ks = lane >> 4;
    const int swz = (fr & 7) << 4;
    const int cb0 = (ks * 16) ^ swz;
    const int cb1 = (ks * 16 + 64) ^ swz;
    const int arowb = wr * 16384 + fr * 128;
    const int browb = 32768 + (wc >> 1) * 16384 + ((wc & 1) * 64 + fr) * 128;

    // staging: wave stages 8 rows (w*8+sr) x 128 B per gload; source col
    // pre-swizzled so LDS dest stays linear (16-B pieces, XOR by row&7 = sr)
    const int sr = lane >> 3;
    const int swzcolB = ((lane & 7) ^ sr) * 16;      // bytes
    const unsigned char* pA[4];
    const unsigned char* pB[4];
#pragma unroll
    for (int g = 0; g < 4; ++g) {
        const int row = g * 64 + w * 8 + sr;
        pA[g] = A + (size_t)bidx[m0 + row] * N_ITEMS + swzcolB;
        pB[g] = A + (size_t)(n0 + row) * N_ITEMS + swzcolB;
    }

    i32x4 acc[8][4] = {};
    i32x4 af[8], af2[8], bf01[4], bf23[4];

#define STA(U, h) do { \
    char* d_ = lds + (((U) & 1) * 65536) + (h) * 16384 + w * 1024; \
    const int k0_ = (U) * 128; \
    gload16(pA[(h)*2+0] + k0_, d_); \
    gload16(pA[(h)*2+1] + k0_, d_ + 8192); } while (0)

#define STB(U, h) do { \
    char* d_ = lds + (((U) & 1) * 65536) + 32768 + (h) * 16384 + w * 1024; \
    const int k0_ = (U) * 128; \
    gload16(pB[(h)*2+0] + k0_, d_); \
    gload16(pB[(h)*2+1] + k0_, d_ + 8192); } while (0)

    // prologue: tile0 fully + tile1.A; drain tile0, keep tile1.A in flight
    STA(0, 0); STA(0, 1); STB(0, 0); STB(0, 1); STA(1, 0); STA(1, 1);
    asm volatile("s_waitcnt vmcnt(4)" ::: "memory");
    __builtin_amdgcn_s_barrier();

    for (int i = 0; i < 15; ++i) {
        const int t1 = 2 * i + 1, t2 = 2 * i + 2, t3 = 2 * i + 3;
        WINDOW(0,     STB(t1, 0), STB(t1, 1), STA(t2, 0), STA(t2, 1), BAR_END_VM4());
        WINDOW(65536, STB(t2, 0), STB(t2, 1), STA(t3, 0), STA(t3, 1), BAR_END_VM4());
    }
    // t=30 (buf0): stage B(31) only, drain fully; t=31 (buf1): bare
    WINDOW(0,     STB(31, 0), STB(31, 1), (void)0, (void)0, BAR_END_VM0());
    WINDOW(65536, (void)0, (void)0, (void)0, (void)0, BAR_END());

    // C epilogue: normalize + self-mask; C/D: col=lane&15, row=ks*4+j (verified)
    const int crow_base = m0 + wr * 128 + ks * 4;
    const int ccol_base = n0 + wc * 64 + fr;
#pragma unroll
    for (int mf = 0; mf < 8; ++mf) {
#pragma unroll
        for (int j = 0; j < 4; ++j) {
            const int b  = crow_base + mf * 16 + j;
            const int ub = bidx[b];
            const float inb = invn[ub];
            float* rp = sim + (size_t)b * N_USERS;
#pragma unroll
            for (int nf = 0; nf < 4; ++nf) {
                const int nn = ccol_base + nf * 16;
                float v = (float)acc[mf][nf][j] * inb * invn[nn];
                if (nn == ub) v = -1e9f;
                rp[nn] = v;
            }
        }
    }
#undef STA
#undef STB
}

// ---------------------------------------------------------------------------
// Kernel 2: per batch row: top-10 via hierarchical argmax (per-thread chunk
// bests + shfl_xor butterfly; only the owner rescans its 32 elems).
// Tie -> lowest index. Softmax(v/0.5) in registers; blend with i8 gathers.
// ---------------------------------------------------------------------------
__global__ __launch_bounds__(256)
void topk_blend(const float* __restrict__ sim,
                const unsigned char* __restrict__ Ai8,
                const float* __restrict__ pred,
                float* __restrict__ out) {
    __shared__ float srow[N_USERS];
    __shared__ float bvs[256];
    __shared__ int   bis[256];

    const int b    = blockIdx.x;
    const int tid  = threadIdx.x;
    const int lane = tid & 63;

    const float* sr = sim + (size_t)b * N_USERS;
    float bv = -1e30f; int bi = 0x7fffffff;
#pragma unroll
    for (int k = 0; k < 8; ++k) {
        const int slot = tid + k * 256;
        float4v v = ((const float4v*)sr)[slot];
        *(float4v*)(srow + slot * 4) = v;
#pragma unroll
        for (int j = 0; j < 4; ++j)
            if (v[j] > bv) { bv = v[j]; bi = slot * 4 + j; }
    }
    bvs[tid] = bv; bis[tid] = bi;
    __syncthreads();

    float topv[TOPK]; int topi[TOPK];
#pragma unroll
    for (int it = 0; it < TOPK; ++it) {
        float fv = bvs[lane]; int fi = bis[lane];
#pragma unroll
        for (int g = 1; g < 4; ++g) {
            float v2 = bvs[lane + g * 64]; int i2 = bis[lane + g * 64];
            if (v2 > fv || (v2 == fv && i2 < fi)) { fv = v2; fi = i2; }
        }
#pragma unroll
        for (int o = 1; o < 64; o <<= 1) {
            float ov = __shfl_xor(fv, o);
            int   oi = __shfl_xor(fi, o);
            if (ov > fv || (ov == fv && oi < fi)) { fv = ov; fi = oi; }
        }
        topv[it] = fv; topi[it] = fi;
        __syncthreads();
        if (tid == ((fi >> 2) & 255)) {
            srow[fi] = -1e30f;
            float nb = -1e30f; int ni = 0x7fffffff;
#pragma unroll
            for (int k = 0; k < 8; ++k) {
                const int slot = tid + k * 256;
                float4v v = *(const float4v*)(srow + slot * 4);
#pragma unroll
                for (int j = 0; j < 4; ++j)
                    if (v[j] > nb) { nb = v[j]; ni = slot * 4 + j; }
            }
            bvs[tid] = nb; bis[tid] = ni;
        }
        __syncthreads();
    }

    float w[TOPK];
    float mx = -1e30f;
#pragma unroll
    for (int k = 0; k < TOPK; ++k) mx = fmaxf(mx, topv[k]);
    float sumw = 0.f;
#pragma unroll
    for (int k = 0; k < TOPK; ++k) {
        w[k] = __expf((topv[k] - mx) * 2.0f);   // 1/TEMP = 2
        sumw += w[k];
    }
    const float scl = 0.3f / sumw;              // fold (1-gamma)
#pragma unroll
    for (int k = 0; k < TOPK; ++k) w[k] *= scl;

    const float* pr = pred + (size_t)b * N_ITEMS;
    float*       po = out  + (size_t)b * N_ITEMS;
#pragma unroll
    for (int h = 0; h < 2; ++h) {
        const int col = h * 2048 + tid * 8;
        float4v p0 = *(const float4v*)(pr + col);
        float4v p1 = *(const float4v*)(pr + col + 4);
        float agg[8];
#pragma unroll
        for (int j = 0; j < 8; ++j) agg[j] = 0.f;
#pragma unroll
        for (int k = 0; k < TOPK; ++k) {
            uchar8 nv = *(const uchar8*)(Ai8 + (size_t)topi[k] * N_ITEMS + col);
#pragma unroll
            for (int j = 0; j < 8; ++j) agg[j] += w[k] * (float)nv[j];
        }
        float4v o0, o1;
#pragma unroll
        for (int j = 0; j < 4; ++j) {
            o0[j] = 0.7f * p0[j] + agg[j];
            o1[j] = 0.7f * p1[j] + agg[j + 4];
        }
        *(float4v*)(po + col)     = o0;
        *(float4v*)(po + col + 4) = o1;
    }
}

extern "C" void kernel_launch(void* const* d_in, const int* in_sizes, int n_in,
                              void* d_out, int out_size, void* d_ws, size_t ws_size,
                              hipStream_t stream) {
    const float* pred = (const float*)d_in[0];
    const float* A    = (const float*)d_in[1];
    const int*   bidx = (const int*)d_in[2];
    float*       out  = (float*)d_out;

    // ws: Ai8 32 MiB | invn 32 KiB (pad 64 KiB) | sim f32 64 MiB
    unsigned char* Ai8  = (unsigned char*)d_ws;
    float*         invn = (float*)((char*)d_ws + (size_t)N_USERS * N_ITEMS);
    float*         sim  = (float*)((char*)d_ws + (size_t)N_USERS * N_ITEMS + 65536);

    convert_rows<<<N_USERS, 256, 0, stream>>>(A, Ai8, invn);
    sim_gemm8<<<dim3(N_USERS / 256, BATCH / 256), 512, 0, stream>>>(Ai8, bidx, invn, sim);
    topk_blend<<<BATCH, 256, 0, stream>>>(sim, Ai8, pred, out);
}